// Round 12
// baseline (209.839 us; speedup 1.0000x reference)
//
#include <hip/hip_runtime.h>
#include <hip/hip_bf16.h>
#include <stdint.h>

// B=8, N=1024, D=256, fp32 in/out.
// R22: prep restructured to take its streaming off the critical path:
//  - prep1 (768 blks): x h/l split + M-build (only outputs xs needs).
//  - xs_fused (2560 blks, 1-D): xs GEMM blocks (0..1023, R21 tiles) +
//    y-prep (512) + pos-softmax (1024) riding behind — their ~48 MB of
//    streaming overlaps xs's MFMA phase instead of running serially.
// All paths are verbatim copies (bit-identical math). sc/blendsm/pv = R21.
// dur_us includes the harness's fixed 41 us workspace-poison fill.
// 5 dispatches: prep1 -> xs_fused -> scores mgemm -> blendsm -> pv_gemm.

#define NB 8
#define NN_ 1024
#define ND 256

typedef __bf16 bf16x8 __attribute__((ext_vector_type(8)));
typedef __bf16 bf16x4 __attribute__((ext_vector_type(4)));
typedef float f32x4 __attribute__((ext_vector_type(4)));

// ---------------- async global->LDS (16B per lane) ----------------
__device__ inline void gl_lds(const __bf16* g, __bf16* l) {
    auto gp = (const __attribute__((address_space(1))) uint32_t*)(uintptr_t)g;
    auto lp = (__attribute__((address_space(3))) uint32_t*)(uintptr_t)l;
    __builtin_amdgcn_global_load_lds(gp, lp, 16, 0, 0);
}

// ---------------- reductions ----------------
__device__ inline float wred_sum(float v) {
#pragma unroll
    for (int o = 32; o; o >>= 1) v += __shfl_xor(v, o, 64);
    return v;
}
__device__ inline float wred_max(float v) {
#pragma unroll
    for (int o = 32; o; o >>= 1) v = fmaxf(v, __shfl_xor(v, o, 64));
    return v;
}

// ---------------- prep1: x h/l split | build M ---------------------------
__global__ __launch_bounds__(256) void prep1_kernel(
    const float* __restrict__ x, const float* __restrict__ U,
    const float* __restrict__ S1, const float* __restrict__ S2,
    __bf16* __restrict__ Xh, __bf16* __restrict__ Xl,
    __bf16* __restrict__ Mh, __bf16* __restrict__ Ml) {
    const int bid = blockIdx.x;
    const int tid = threadIdx.x;

    if (bid < 512) {
        const int n4 = NB * NN_ * ND / 4;
        int i = bid * 256 + tid;
        for (; i < n4; i += 512 * 256) {
            float4 v = ((const float4*)x)[i];
            bf16x4 h, l;
            h[0] = (__bf16)v.x; l[0] = (__bf16)(v.x - (float)h[0]);
            h[1] = (__bf16)v.y; l[1] = (__bf16)(v.y - (float)h[1]);
            h[2] = (__bf16)v.z; l[2] = (__bf16)(v.z - (float)h[2]);
            h[3] = (__bf16)v.w; l[3] = (__bf16)(v.w - (float)h[3]);
            ((bf16x4*)Xh)[i] = h;
            ((bf16x4*)Xl)[i] = l;
        }
    } else {
        const int n = bid - 512, j = tid;
        float a1 = 0.f, a2 = 0.f;
#pragma unroll 4
        for (int c = 0; c < ND; ++c) {
            const float un = U[c * ND + n];
            const float uj = U[c * ND + j];
            a1 = fmaf(fabsf(S1[c]) * un, uj, a1);
            a2 = fmaf(fabsf(S2[c]) * un, uj, a2);
        }
        const __bf16 h1 = (__bf16)a1, h2 = (__bf16)a2;
        Mh[n * ND + j] = h1;           Ml[n * ND + j] = (__bf16)(a1 - (float)h1);
        Mh[65536 + n * ND + j] = h2;   Ml[65536 + n * ND + j] = (__bf16)(a2 - (float)h2);
    }
}

// ---------------- xs_fused: xs GEMM | y prep | pos softmax ---------------
// 1-D grid 2560: bids 0..1023 = xs GEMM (BM64/BN64/BK32, dbuf LDS, R21
// structure); 1024..1535 = y h/l split + yt transpose; 1536..2559 = pos
// softmax. GEMM blocks launch first; the streaming blocks overlap them.
__global__ __launch_bounds__(256) void xs_fused(
    const __bf16* __restrict__ Ah, const __bf16* __restrict__ Al,
    const __bf16* __restrict__ Bh, const __bf16* __restrict__ Bl,
    __bf16* __restrict__ Ch, __bf16* __restrict__ Cl,
    const float* __restrict__ y, __bf16* __restrict__ yt,
    __bf16* __restrict__ Yh, __bf16* __restrict__ Yl,
    const float* __restrict__ coords, const float* __restrict__ pos_emb,
    const float* __restrict__ p_temp, float* __restrict__ posS) {
    __shared__ __bf16 sm2[2][8192];   // 32 KB; xs: [buf][A:0..4095|B:4096..]
    const int bid = blockIdx.x;
    const int tid = threadIdx.x;

    if (bid < 1024) {
        constexpr int BM = 64, BK = 32, BN = 64;
        constexpr int K = 256, N = 256;
        const int z = bid >> 9;
        const int r = bid & 511;
        const int bm = (r >> 2) * BM;
        const int bn = (r & 3) * BN;
        const __bf16* Bh_ = Bh + (long)z * 65536;
        const __bf16* Bl_ = Bl + (long)z * 65536;

        const int wave = tid >> 6, lane = tid & 63;
        const int wm = wave >> 1, wn = wave & 1;
        const int quad = lane >> 4, l16 = lane & 15;
        const int srow = lane >> 2, slot = lane & 3;

        f32x4 acc[2][2];
#pragma unroll
        for (int i = 0; i < 2; ++i)
#pragma unroll
            for (int j = 0; j < 2; ++j) acc[i][j] = (f32x4){0.f, 0.f, 0.f, 0.f};

        auto stage = [&](int sel, int k0) {
            const int r0 = wave * 16;
            const int row = r0 + srow;
            const int chunk = slot ^ ((row >> 1) & 3);
            const long ga = (long)(bm + row) * K + k0 + chunk * 8;
            gl_lds(Ah + ga, &sm2[sel][r0 * 32]);
            gl_lds(Al + ga, &sm2[sel][BM * BK + r0 * 32]);
            const long gb = (long)(bn + row) * K + k0 + chunk * 8;
            gl_lds(Bh_ + gb, &sm2[sel][4096 + r0 * 32]);
            gl_lds(Bl_ + gb, &sm2[sel][4096 + BN * BK + r0 * 32]);
        };

        stage(0, 0);
        __syncthreads();
        int cur = 0;
        for (int k0 = 0; k0 < K; k0 += BK) {
            if (k0 + BK < K) stage(cur ^ 1, k0 + BK);

            bf16x8 a_h[2], a_l[2], b_h[2], b_l[2];
#pragma unroll
            for (int mi = 0; mi < 2; ++mi) {
                const int row = wm * 32 + mi * 16 + l16;
                const int off = row * 32 + ((quad ^ ((row >> 1) & 3)) * 8);
                a_h[mi] = *(const bf16x8*)&sm2[cur][off];
                a_l[mi] = *(const bf16x8*)&sm2[cur][BM * BK + off];
            }
#pragma unroll
            for (int ni = 0; ni < 2; ++ni) {
                const int row = wn * 32 + ni * 16 + l16;
                const int off = row * 32 + ((quad ^ ((row >> 1) & 3)) * 8);
                b_h[ni] = *(const bf16x8*)&sm2[cur][4096 + off];
                b_l[ni] = *(const bf16x8*)&sm2[cur][4096 + BN * BK + off];
            }
#pragma unroll
            for (int mi = 0; mi < 2; ++mi)
#pragma unroll
                for (int ni = 0; ni < 2; ++ni) {
                    acc[mi][ni] = __builtin_amdgcn_mfma_f32_16x16x32_bf16(
                        a_h[mi], b_h[ni], acc[mi][ni], 0, 0, 0);
                    acc[mi][ni] = __builtin_amdgcn_mfma_f32_16x16x32_bf16(
                        a_h[mi], b_l[ni], acc[mi][ni], 0, 0, 0);
                    acc[mi][ni] = __builtin_amdgcn_mfma_f32_16x16x32_bf16(
                        a_l[mi], b_h[ni], acc[mi][ni], 0, 0, 0);
                }

            __syncthreads();
            cur ^= 1;
        }

        __bf16* Ch_ = Ch + (long)z * (NB * NN_ * ND);
        __bf16* Cl_ = Cl + (long)z * (NB * NN_ * ND);
#pragma unroll
        for (int mi = 0; mi < 2; ++mi) {
            const int row0 = bm + wm * 32 + mi * 16 + quad * 4;
#pragma unroll
            for (int ni = 0; ni < 2; ++ni) {
                const int col = bn + wn * 32 + ni * 16 + l16;
#pragma unroll
                for (int r2 = 0; r2 < 4; ++r2) {
                    const float v = acc[mi][ni][r2];
                    const long idx = (long)(row0 + r2) * N + col;
                    const __bf16 h = (__bf16)v;
                    Ch_[idx] = h;
                    Cl_[idx] = (__bf16)(v - (float)h);
                }
            }
        }
    } else if (bid < 1536) {
        __bf16 (*t)[72] = (__bf16(*)[72])&sm2[0][0];   // 9216 B
        const int rem = bid - 1024;
        const int b = rem >> 6;
        const int m0 = (rem & 15) * 64, d0 = ((rem >> 4) & 3) * 64;
        const int c = tid & 15;
        const int r = tid >> 4;
#pragma unroll
        for (int p = 0; p < 4; ++p) {
            const int row = r + p * 16;
            const long gi = ((long)b * NN_ + m0 + row) * ND + d0 + c * 4;
            float4 v = *(const float4*)(y + gi);
            bf16x4 h, l;
            h[0] = (__bf16)v.x; l[0] = (__bf16)(v.x - (float)h[0]);
            h[1] = (__bf16)v.y; l[1] = (__bf16)(v.y - (float)h[1]);
            h[2] = (__bf16)v.z; l[2] = (__bf16)(v.z - (float)h[2]);
            h[3] = (__bf16)v.w; l[3] = (__bf16)(v.w - (float)h[3]);
            *(bf16x4*)(Yh + gi) = h;
            *(bf16x4*)(Yl + gi) = l;
            t[c * 4 + 0][row] = h[0]; t[c * 4 + 1][row] = h[1];
            t[c * 4 + 2][row] = h[2]; t[c * 4 + 3][row] = h[3];
        }
        __syncthreads();
#pragma unroll
        for (int p = 0; p < 4; ++p) {
            const int d = r + p * 16;
            bf16x4 o;
            o[0] = t[d][c * 4 + 0]; o[1] = t[d][c * 4 + 1];
            o[2] = t[d][c * 4 + 2]; o[3] = t[d][c * 4 + 3];
            *(bf16x4*)(yt + ((long)b * ND + d0 + d) * NN_ + m0 + c * 4) = o;
        }
    } else {
        float* red = (float*)&sm2[0][0];
        const int n = bid - 1536;
        const float pt = -fabsf(p_temp[0]);
        float pe[6];
#pragma unroll
        for (int c = 0; c < 6; ++c) pe[c] = pos_emb[n * 6 + c];
        const float* cr = coords + (long)n * NN_ * 6;
        float l[4];
#pragma unroll
        for (int j = 0; j < 4; ++j) {
            const int m = j * 256 + tid;
            const float2* cp = (const float2*)(cr + (long)m * 6);
            float2 c0 = cp[0], c1 = cp[1], c2 = cp[2];
            l[j] = pt * (c0.x * pe[0] + c0.y * pe[1] + c1.x * pe[2] +
                         c1.y * pe[3] + c2.x * pe[4] + c2.y * pe[5]);
        }
        float mx = fmaxf(fmaxf(l[0], l[1]), fmaxf(l[2], l[3]));
        mx = wred_max(mx);
        __syncthreads();
        if ((tid & 63) == 0) red[tid >> 6] = mx;
        __syncthreads();
        mx = fmaxf(fmaxf(red[0], red[1]), fmaxf(red[2], red[3]));
        float e[4], s = 0.f;
#pragma unroll
        for (int j = 0; j < 4; ++j) { e[j] = __expf(l[j] - mx); s += e[j]; }
        s = wred_sum(s);
        __syncthreads();
        if ((tid & 63) == 0) red[4 + (tid >> 6)] = s;
        __syncthreads();
        s = red[4] + red[5] + red[6] + red[7];
        const float inv = 1.f / s;
#pragma unroll
        for (int j = 0; j < 4; ++j)
            posS[(long)n * NN_ + j * 256 + tid] = e[j] * inv;
    }
}

// ---------------- scores: S[z] = (XS_z @ Y_b^T)*alpha, fp32 out -------------
// 1-D grid 1024, XCD-aware decode: xcd=bid&7 owns z=2*xcd+(j>>6) (both z of
// one batch b=xcd share the Y panel) -> per-XCD L2 working set 3 MB.
__global__ __launch_bounds__(256) void mgemm_sc(
    const __bf16* __restrict__ Ah, const __bf16* __restrict__ Al,
    const __bf16* __restrict__ Bh, const __bf16* __restrict__ Bl,
    float* __restrict__ C, int N, int K,
    long sA1, long sA2, long sB1, long sC, float alpha) {
    constexpr int BM = 128, BK = 32, BN = 128;
    __shared__ __bf16 As[2 * BM * BK];
    __shared__ __bf16 Bs[2 * BN * BK];

    const int bid = blockIdx.x;
    const int xcd = bid & 7;
    const int j   = bid >> 3;
    const int z   = 2 * xcd + (j >> 6);
    const int t   = j & 63;
    const int bm  = (t >> 3) * BM;
    const int bn  = (t & 7) * BN;

    const long aoff = (long)(z >> 1) * sA1 + (long)(z & 1) * sA2;
    const long boff = (long)(z >> 1) * sB1;
    Ah += aoff; Al += aoff;
    Bh += boff; Bl += boff;

    const int tid = threadIdx.x;
    const int wave = tid >> 6, lane = tid & 63;
    const int wm = wave >> 1, wn = wave & 1;
    const int quad = lane >> 4, l16 = lane & 15;

    f32x4 acc[4][4];
#pragma unroll
    for (int i = 0; i < 4; ++i)
#pragma unroll
        for (int jj = 0; jj < 4; ++jj) acc[i][jj] = (f32x4){0.f, 0.f, 0.f, 0.f};

    const int srow = lane >> 2;
    const int slot = lane & 3;

    for (int k0 = 0; k0 < K; k0 += BK) {
        __syncthreads();
#pragma unroll
        for (int i = 0; i < 2; ++i) {
            const int r0 = wave * 32 + i * 16;
            const int row = r0 + srow;
            const int chunk = slot ^ ((row >> 1) & 3);
            const long ga = (long)(bm + row) * K + k0 + chunk * 8;
            gl_lds(Ah + ga, &As[r0 * 32]);
            gl_lds(Al + ga, &As[BM * BK + r0 * 32]);
            const long gb = (long)(bn + row) * K + k0 + chunk * 8;
            gl_lds(Bh + gb, &Bs[r0 * 32]);
            gl_lds(Bl + gb, &Bs[BN * BK + r0 * 32]);
        }
        __syncthreads();

        bf16x8 a_h[4], a_l[4], b_h[4], b_l[4];
#pragma unroll
        for (int mi = 0; mi < 4; ++mi) {
            const int row = wm * 64 + mi * 16 + l16;
            const int off = row * 32 + ((quad ^ ((row >> 1) & 3)) * 8);
            a_h[mi] = *(const bf16x8*)&As[off];
            a_l[mi] = *(const bf16x8*)&As[BM * BK + off];
        }
#pragma unroll
        for (int ni = 0; ni < 4; ++ni) {
            const int row = wn * 64 + ni * 16 + l16;
            const int off = row * 32 + ((quad ^ ((row >> 1) & 3)) * 8);
            b_h[ni] = *(const bf16x8*)&Bs[off];
            b_l[ni] = *(const bf16x8*)&Bs[BN * BK + off];
        }
#pragma unroll
        for (int mi = 0; mi < 4; ++mi)
#pragma unroll
            for (int ni = 0; ni < 4; ++ni) {
                acc[mi][ni] = __builtin_amdgcn_mfma_f32_16x16x32_bf16(
                    a_h[mi], b_h[ni], acc[mi][ni], 0, 0, 0);
                acc[mi][ni] = __builtin_amdgcn_mfma_f32_16x16x32_bf16(
                    a_h[mi], b_l[ni], acc[mi][ni], 0, 0, 0);
                acc[mi][ni] = __builtin_amdgcn_mfma_f32_16x16x32_bf16(
                    a_l[mi], b_h[ni], acc[mi][ni], 0, 0, 0);
            }
    }

    C += (long)z * sC;
#pragma unroll
    for (int mi = 0; mi < 4; ++mi) {
        const int row0 = bm + wm * 64 + mi * 16 + quad * 4;
#pragma unroll
        for (int ni = 0; ni < 4; ++ni) {
            const int col = bn + wn * 64 + ni * 16 + l16;
#pragma unroll
            for (int r = 0; r < 4; ++r)
                C[(long)(row0 + r) * NN_ + col] = acc[mi][ni][r] * alpha;
        }
    }
}

// ---------------- blendsm: softmax+blend+entropy+route, P -> global --------
// Grid 2048 x 256 thr (4 waves). Block owns (b = blk&7, rows 4*(blk>>3)..+3).
// Wave w owns one row fully: softmax/entropy/route wave-local, no barriers.
__global__ __launch_bounds__(256, 8) void blendsm_kernel(
    const float* __restrict__ S, const float* __restrict__ pos,
    const float* __restrict__ gating, const float* __restrict__ h_temp,
    __bf16* __restrict__ P, float* __restrict__ heat) {
    const int b = blockIdx.x & 7;
    const int n = (blockIdx.x >> 3) * 4 + (threadIdx.x >> 6);
    const int lane = threadIdx.x & 63;

    const float g = 1.f / (1.f + __expf(-gating[0]));
    const float cg = 1.f - g;
    const float ht = h_temp[0];

    const float* r0p = S + ((long)(b * 2 + 0) * NN_ + n) * NN_;
    const float* r1p = S + ((long)(b * 2 + 1) * NN_ + n) * NN_;

    f32x4 a0[4], a1[4];
#pragma unroll
    for (int j = 0; j < 4; ++j) {
        a0[j] = *(const f32x4*)(r0p + j * 256 + lane * 4);
        a1[j] = *(const f32x4*)(r1p + j * 256 + lane * 4);
    }
    // row max (in-wave)
    float m0 = -3.4e38f, m1 = -3.4e38f;
#pragma unroll
    for (int j = 0; j < 4; ++j) {
        m0 = fmaxf(m0, fmaxf(fmaxf(a0[j][0], a0[j][1]), fmaxf(a0[j][2], a0[j][3])));
        m1 = fmaxf(m1, fmaxf(fmaxf(a1[j][0], a1[j][1]), fmaxf(a1[j][2], a1[j][3])));
    }
    m0 = wred_max(m0); m1 = wred_max(m1);
    // exp + sum
    float s0 = 0.f, s1 = 0.f;
#pragma unroll
    for (int j = 0; j < 4; ++j) {
        a0[j][0] = __expf(a0[j][0] - m0); a0[j][1] = __expf(a0[j][1] - m0);
        a0[j][2] = __expf(a0[j][2] - m0); a0[j][3] = __expf(a0[j][3] - m0);
        s0 += a0[j][0] + a0[j][1] + a0[j][2] + a0[j][3];
        a1[j][0] = __expf(a1[j][0] - m1); a1[j][1] = __expf(a1[j][1] - m1);
        a1[j][2] = __expf(a1[j][2] - m1); a1[j][3] = __expf(a1[j][3] - m1);
        s1 += a1[j][0] + a1[j][1] + a1[j][2] + a1[j][3];
    }
    s0 = wred_sum(s0); s1 = wred_sum(s1);
    const float i0 = 1.f / s0, i1 = 1.f / s1;
    // blend + entropy
    const float* pr = pos + (long)n * NN_;
    float e0 = 0.f, e1 = 0.f;
#pragma unroll
    for (int j = 0; j < 4; ++j) {
        const f32x4 pv = *(const f32x4*)(pr + j * 256 + lane * 4);
        a0[j][0] = cg * a0[j][0] * i0 + g * pv[0];
        a0[j][1] = cg * a0[j][1] * i0 + g * pv[1];
        a0[j][2] = cg * a0[j][2] * i0 + g * pv[2];
        a0[j][3] = cg * a0[j][3] * i0 + g * pv[3];
        a1[j][0] = cg * a1[j][0] * i1 + g * pv[0];
        a1[j][1] = cg * a1[j][1] * i1 + g * pv[1];
        a1[j][2] = cg * a1[j][2] * i1 + g * pv[2];
        a1[j][3] = cg * a1[j][3] * i1 + g * pv[3];
        e0 -= a0[j][0] * __logf(a0[j][0] + 1e-8f) + a0[j][1] * __logf(a0[j][1] + 1e-8f) +
              a0[j][2] * __logf(a0[j][2] + 1e-8f) + a0[j][3] * __logf(a0[j][3] + 1e-8f);
        e1 -= a1[j][0] * __logf(a1[j][0] + 1e-8f) + a1[j][1] * __logf(a1[j][1] + 1e-8f) +
              a1[j][2] * __logf(a1[j][2] + 1e-8f) + a1[j][3] * __logf(a1[j][3] + 1e-8f);
    }
    e0 = wred_sum(e0); e1 = wred_sum(e1);
    const float hm0 = 2.f - 2.f / (1.f + __expf(-ht * e0));
    const float hm1 = 2.f - 2.f / (1.f + __expf(-ht * e1));
    const bool fg = (hm0 >= hm1);
    if (lane == 0) heat[(long)b * NN_ + n] = fg ? hm0 : hm1;
    // selected P row -> global bf16
    __bf16* prow = P + ((long)b * NN_ + n) * NN_;
#pragma unroll
    for (int j = 0; j < 4; ++j) {
        const f32x4 v = fg ? a0[j] : a1[j];
        bf16x4 o;
        o[0] = (__bf16)v[0]; o[1] = (__bf16)v[1];
        o[2] = (__bf16)v[2]; o[3] = (__bf16)v[3];
        *(bf16x4*)(prow + j * 256 + lane * 4) = o;
    }
}

// ---------------- pv_gemm v2: out[b] = P[b] @ yt[b]^T ---------------------
// BM32/BK32/BN64, 256 thr / 4 waves, double-buffered LDS (12 KB).
// 1-D grid 1024 = 8 b (bid&7, XCD-local) x 32 m x 4 n -> 4096 waves.
__global__ __launch_bounds__(256) void pv_gemm(
    const __bf16* __restrict__ A, const __bf16* __restrict__ Bm,
    float* __restrict__ C) {
    constexpr int BM = 32, BK = 32, BN = 64;
    __shared__ __bf16 As[2][BM * BK];
    __shared__ __bf16 Bs[2][BN * BK];

    const int bid = blockIdx.x;
    const int b   = bid & 7;
    const int j   = bid >> 3;           // 0..127
    const int bm  = (j >> 2) * BM;      // 32 m-tiles
    const int bn  = (j & 3) * BN;       // 4 n-tiles

    A  += (long)b * NN_ * NN_;
    Bm += (long)b * ND * NN_;
    C  += (long)b * NN_ * ND;

    const int tid = threadIdx.x;
    const int wave = tid >> 6, lane = tid & 63;
    const int wm = wave >> 1, wn = wave & 1;
    const int quad = lane >> 4, l16 = lane & 15;
    const int srow = lane >> 2, slot = lane & 3;

    f32x4 acc[2];
    acc[0] = (f32x4){0.f, 0.f, 0.f, 0.f};
    acc[1] = (f32x4){0.f, 0.f, 0.f, 0.f};

    auto stage = [&](int sel, int k0) {
        if (wave < 2) {                 // A: 32 rows = 2 waves x 16
            const int row = wave * 16 + srow;
            const int chunk = slot ^ ((row >> 1) & 3);
            gl_lds(A + (long)(bm + row) * NN_ + k0 + chunk * 8,
                   &As[sel][wave * 16 * 32]);
        }
        {                               // B: 64 rows = 4 waves x 16
            const int row = wave * 16 + srow;
            const int chunk = slot ^ ((row >> 1) & 3);
            gl_lds(Bm + (long)(bn + row) * NN_ + k0 + chunk * 8,
                   &Bs[sel][wave * 16 * 32]);
        }
    };

    stage(0, 0);
    __syncthreads();
    int cur = 0;
    for (int k0 = 0; k0 < NN_; k0 += BK) {
        if (k0 + BK < NN_) stage(cur ^ 1, k0 + BK);

        const int arow = wm * 16 + l16;
        const int aoff = arow * 32 + ((quad ^ ((arow >> 1) & 3)) * 8);
        bf16x8 a = *(const bf16x8*)&As[cur][aoff];
#pragma unroll
        for (int ni = 0; ni < 2; ++ni) {
            const int brow = wn * 32 + ni * 16 + l16;
            const int boff = brow * 32 + ((quad ^ ((brow >> 1) & 3)) * 8);
            bf16x8 bb = *(const bf16x8*)&Bs[cur][boff];
            acc[ni] = __builtin_amdgcn_mfma_f32_16x16x32_bf16(
                a, bb, acc[ni], 0, 0, 0);
        }

        __syncthreads();
        cur ^= 1;
    }

    const int row0 = bm + wm * 16 + quad * 4;
#pragma unroll
    for (int ni = 0; ni < 2; ++ni) {
        const int col = bn + wn * 32 + ni * 16 + l16;
#pragma unroll
        for (int r = 0; r < 4; ++r)
            C[(long)(row0 + r) * ND + col] = acc[ni][r];
    }
}

extern "C" void kernel_launch(void* const* d_in, const int* in_sizes, int n_in,
                              void* d_out, int out_size, void* d_ws, size_t ws_size,
                              hipStream_t stream) {
    const float* x      = (const float*)d_in[0];
    const float* y      = (const float*)d_in[1];
    const float* coords = (const float*)d_in[2];
    const float* U      = (const float*)d_in[3];
    const float* S1p    = (const float*)d_in[4];
    const float* S2p    = (const float*)d_in[5];
    const float* gating = (const float*)d_in[6];
    const float* h_temp = (const float*)d_in[7];
    const float* p_temp = (const float*)d_in[8];
    const float* pos_emb= (const float*)d_in[9];

    float* out  = (float*)d_out;
    float* heat = out + (long)NB * NN_ * ND;

    // workspace (~105 MB)
    char* ws = (char*)d_ws;
    const long MB = 1 << 20;
    float*  Sf  = (float*)(ws);               // 64 MB [16][1024][1024]
    float*  pos = (float*)(ws + 64 * MB);     // 4 MB
    __bf16* Xh  = (__bf16*)(ws + 68 * MB);    // 4 MB
    __bf16* Xl  = (__bf16*)(ws + 72 * MB);    // 4 MB
    __bf16* XSh = (__bf16*)(ws + 76 * MB);    // 8 MB [2][8192][256]
    __bf16* XSl = (__bf16*)(ws + 84 * MB);    // 8 MB
    __bf16* yt  = (__bf16*)(ws + 92 * MB);    // 4 MB [8][256][1024]
    __bf16* Yh  = (__bf16*)(ws + 96 * MB);    // 4 MB
    __bf16* Yl  = (__bf16*)(ws + 100 * MB);   // 4 MB
    __bf16* Mh  = (__bf16*)(ws + 104 * MB);   // 256 KB [2][256][256]
    __bf16* Ml  = Mh + 2 * 65536;             // 256 KB
    // P overlays XSh/XSl (16 MB, dead after mgemm_sc)
    __bf16* Pb  = (__bf16*)(ws + 76 * MB);    // 16 MB [8][1024][1024]

    const long ND2 = (long)NN_ * ND;          // 262144
    const long BND = (long)NB * ND2;          // 2097152

    // 1) x split + M build (only what xs needs)
    prep1_kernel<<<dim3(768), 256, 0, stream>>>(
        x, U, S1p, S2p, Xh, Xl, Mh, Ml);

    // 2) xs GEMM + y prep + pos softmax (streaming rides behind the GEMM)
    xs_fused<<<dim3(2560), 256, 0, stream>>>(
        Xh, Xl, Mh, Ml, XSh, XSl,
        y, yt, Yh, Yl, coords, pos_emb, p_temp, pos);

    // 3) scores: S[b*2+br] = (XS_br[b] @ Y[b]^T) * D^-0.5  (XCD-swizzled)
    mgemm_sc<<<dim3(1024), 256, 0, stream>>>(
        XSh, XSl, Yh, Yl, Sf, NN_, ND,
        ND2, BND, ND2, (long)NN_ * NN_, 0.0625f);

    // 4) blend + entropy + route -> P (bf16), heat
    blendsm_kernel<<<dim3(2048), 256, 0, stream>>>(
        Sf, pos, gating, h_temp, Pb, heat);

    // 5) out[b] = P[b] @ yt[b]^T  (XCD-local)
    pv_gemm<<<dim3(1024), 256, 0, stream>>>(Pb, yt, out);

    (void)in_sizes; (void)n_in; (void)out_size; (void)ws_size;
}

// Round 13
// 202.035 us; speedup vs baseline: 1.0386x; 1.0386x over previous
//
#include <hip/hip_runtime.h>
#include <hip/hip_bf16.h>
#include <stdint.h>

// B=8, N=1024, D=256, fp32 in/out.
// R23: revert R22's fusion experiment (regressed 196->210: fused streaming
// blocks inherited the GEMM's 32KB LDS footprint and saturated HBM under
// the GEMM's staging). Back to R21, the best-measured config (196.4 us),
// with one bit-identical micro-change: unroll-4 on the M-build FMA chain.
// dur_us includes the harness's fixed 41 us workspace-poison fill.
// 5 dispatches: prep -> xs mgemm -> scores mgemm -> blendsm -> pv_gemm.

#define NB 8
#define NN_ 1024
#define ND 256

typedef __bf16 bf16x8 __attribute__((ext_vector_type(8)));
typedef __bf16 bf16x4 __attribute__((ext_vector_type(4)));
typedef float f32x4 __attribute__((ext_vector_type(4)));

// ---------------- async global->LDS (16B per lane) ----------------
__device__ inline void gl_lds(const __bf16* g, __bf16* l) {
    auto gp = (const __attribute__((address_space(1))) uint32_t*)(uintptr_t)g;
    auto lp = (__attribute__((address_space(3))) uint32_t*)(uintptr_t)l;
    __builtin_amdgcn_global_load_lds(gp, lp, 16, 0, 0);
}

// ---------------- reductions ----------------
__device__ inline float wred_sum(float v) {
#pragma unroll
    for (int o = 32; o; o >>= 1) v += __shfl_xor(v, o, 64);
    return v;
}
__device__ inline float wred_max(float v) {
#pragma unroll
    for (int o = 32; o; o >>= 1) v = fmaxf(v, __shfl_xor(v, o, 64));
    return v;
}

// ---------------- fused prep: pos softmax | x split | y prep | build M ------
__global__ __launch_bounds__(256) void prep_kernel(
    const float* __restrict__ coords, const float* __restrict__ pos_emb,
    const float* __restrict__ p_temp, const float* __restrict__ x,
    const float* __restrict__ y, const float* __restrict__ U,
    const float* __restrict__ S1, const float* __restrict__ S2,
    float* __restrict__ posS, __bf16* __restrict__ Xh, __bf16* __restrict__ Xl,
    __bf16* __restrict__ yt, __bf16* __restrict__ Yh, __bf16* __restrict__ Yl,
    __bf16* __restrict__ Mh, __bf16* __restrict__ Ml) {
    __shared__ char sm[9216 + 64];
    const int bid = blockIdx.x;
    const int tid = threadIdx.x;

    if (bid < 1024) {
        float* red = (float*)sm;
        const int n = bid;
        const float pt = -fabsf(p_temp[0]);
        float pe[6];
#pragma unroll
        for (int c = 0; c < 6; ++c) pe[c] = pos_emb[n * 6 + c];
        const float* cr = coords + (long)n * NN_ * 6;
        float l[4];
#pragma unroll
        for (int j = 0; j < 4; ++j) {
            const int m = j * 256 + tid;
            const float2* cp = (const float2*)(cr + (long)m * 6);
            float2 c0 = cp[0], c1 = cp[1], c2 = cp[2];
            l[j] = pt * (c0.x * pe[0] + c0.y * pe[1] + c1.x * pe[2] +
                         c1.y * pe[3] + c2.x * pe[4] + c2.y * pe[5]);
        }
        float mx = fmaxf(fmaxf(l[0], l[1]), fmaxf(l[2], l[3]));
        mx = wred_max(mx);
        __syncthreads();
        if ((tid & 63) == 0) red[tid >> 6] = mx;
        __syncthreads();
        mx = fmaxf(fmaxf(red[0], red[1]), fmaxf(red[2], red[3]));
        float e[4], s = 0.f;
#pragma unroll
        for (int j = 0; j < 4; ++j) { e[j] = __expf(l[j] - mx); s += e[j]; }
        s = wred_sum(s);
        __syncthreads();
        if ((tid & 63) == 0) red[4 + (tid >> 6)] = s;
        __syncthreads();
        s = red[4] + red[5] + red[6] + red[7];
        const float inv = 1.f / s;
#pragma unroll
        for (int j = 0; j < 4; ++j)
            posS[(long)n * NN_ + j * 256 + tid] = e[j] * inv;
    } else if (bid < 1536) {
        const int n4 = NB * NN_ * ND / 4;
        int i = (bid - 1024) * 256 + tid;
        for (; i < n4; i += 512 * 256) {
            float4 v = ((const float4*)x)[i];
            bf16x4 h, l;
            h[0] = (__bf16)v.x; l[0] = (__bf16)(v.x - (float)h[0]);
            h[1] = (__bf16)v.y; l[1] = (__bf16)(v.y - (float)h[1]);
            h[2] = (__bf16)v.z; l[2] = (__bf16)(v.z - (float)h[2]);
            h[3] = (__bf16)v.w; l[3] = (__bf16)(v.w - (float)h[3]);
            ((bf16x4*)Xh)[i] = h;
            ((bf16x4*)Xl)[i] = l;
        }
    } else if (bid < 2048) {
        __bf16 (*t)[72] = (__bf16(*)[72])sm;
        const int rem = bid - 1536;
        const int b = rem >> 6;
        const int m0 = (rem & 15) * 64, d0 = ((rem >> 4) & 3) * 64;
        const int c = tid & 15;
        const int r = tid >> 4;
#pragma unroll
        for (int p = 0; p < 4; ++p) {
            const int row = r + p * 16;
            const long gi = ((long)b * NN_ + m0 + row) * ND + d0 + c * 4;
            float4 v = *(const float4*)(y + gi);
            bf16x4 h, l;
            h[0] = (__bf16)v.x; l[0] = (__bf16)(v.x - (float)h[0]);
            h[1] = (__bf16)v.y; l[1] = (__bf16)(v.y - (float)h[1]);
            h[2] = (__bf16)v.z; l[2] = (__bf16)(v.z - (float)h[2]);
            h[3] = (__bf16)v.w; l[3] = (__bf16)(v.w - (float)h[3]);
            *(bf16x4*)(Yh + gi) = h;
            *(bf16x4*)(Yl + gi) = l;
            t[c * 4 + 0][row] = h[0]; t[c * 4 + 1][row] = h[1];
            t[c * 4 + 2][row] = h[2]; t[c * 4 + 3][row] = h[3];
        }
        __syncthreads();
#pragma unroll
        for (int p = 0; p < 4; ++p) {
            const int d = r + p * 16;
            bf16x4 o;
            o[0] = t[d][c * 4 + 0]; o[1] = t[d][c * 4 + 1];
            o[2] = t[d][c * 4 + 2]; o[3] = t[d][c * 4 + 3];
            *(bf16x4*)(yt + ((long)b * ND + d0 + d) * NN_ + m0 + c * 4) = o;
        }
    } else {
        const int n = bid - 2048, j = tid;
        float a1 = 0.f, a2 = 0.f;
#pragma unroll 4
        for (int c = 0; c < ND; ++c) {
            const float un = U[c * ND + n];
            const float uj = U[c * ND + j];
            a1 = fmaf(fabsf(S1[c]) * un, uj, a1);
            a2 = fmaf(fabsf(S2[c]) * un, uj, a2);
        }
        const __bf16 h1 = (__bf16)a1, h2 = (__bf16)a2;
        Mh[n * ND + j] = h1;           Ml[n * ND + j] = (__bf16)(a1 - (float)h1);
        Mh[65536 + n * ND + j] = h2;   Ml[65536 + n * ND + j] = (__bf16)(a2 - (float)h2);
    }
}

// ---------------- xs = x @ M_k (split x3, bf16 h/l out) ----------------
// v2: BM64/BN64/BK32, grid (4,128,2)=1024 blocks -> 4096 waves (16/CU).
// Double-buffered LDS (32 KB), stage-before-compute, 1 barrier/K-step.
__global__ __launch_bounds__(256) void mgemm_xs(
    const __bf16* __restrict__ Ah, const __bf16* __restrict__ Al,
    const __bf16* __restrict__ Bh, const __bf16* __restrict__ Bl,
    __bf16* __restrict__ Ch, __bf16* __restrict__ Cl,
    int M, int N, int K, long sB1, long sC) {
    constexpr int BM = 64, BK = 32, BN = 64;
    __shared__ __bf16 As[2][2 * BM * BK];   // [buf][h:0 | l:BM*BK]
    __shared__ __bf16 Bs[2][2 * BN * BK];

    const int z = blockIdx.z;
    Bh += (long)z * sB1; Bl += (long)z * sB1;

    const int tid = threadIdx.x;
    const int bm = blockIdx.y * BM, bn = blockIdx.x * BN;
    const int wave = tid >> 6, lane = tid & 63;
    const int wm = wave >> 1, wn = wave & 1;
    const int quad = lane >> 4, l16 = lane & 15;
    const int srow = lane >> 2, slot = lane & 3;

    f32x4 acc[2][2];
#pragma unroll
    for (int i = 0; i < 2; ++i)
#pragma unroll
        for (int j = 0; j < 2; ++j) acc[i][j] = (f32x4){0.f, 0.f, 0.f, 0.f};

    auto stage = [&](int sel, int k0) {
        const int r0 = wave * 16;
        const int row = r0 + srow;
        const int chunk = slot ^ ((row >> 1) & 3);
        const long ga = (long)(bm + row) * K + k0 + chunk * 8;
        gl_lds(Ah + ga, &As[sel][r0 * 32]);
        gl_lds(Al + ga, &As[sel][BM * BK + r0 * 32]);
        const long gb = (long)(bn + row) * K + k0 + chunk * 8;
        gl_lds(Bh + gb, &Bs[sel][r0 * 32]);
        gl_lds(Bl + gb, &Bs[sel][BN * BK + r0 * 32]);
    };

    stage(0, 0);
    __syncthreads();
    int cur = 0;
    for (int k0 = 0; k0 < K; k0 += BK) {
        if (k0 + BK < K) stage(cur ^ 1, k0 + BK);

        bf16x8 a_h[2], a_l[2], b_h[2], b_l[2];
#pragma unroll
        for (int mi = 0; mi < 2; ++mi) {
            const int row = wm * 32 + mi * 16 + l16;
            const int off = row * 32 + ((quad ^ ((row >> 1) & 3)) * 8);
            a_h[mi] = *(const bf16x8*)&As[cur][off];
            a_l[mi] = *(const bf16x8*)&As[cur][BM * BK + off];
        }
#pragma unroll
        for (int ni = 0; ni < 2; ++ni) {
            const int row = wn * 32 + ni * 16 + l16;
            const int off = row * 32 + ((quad ^ ((row >> 1) & 3)) * 8);
            b_h[ni] = *(const bf16x8*)&Bs[cur][off];
            b_l[ni] = *(const bf16x8*)&Bs[cur][BN * BK + off];
        }
#pragma unroll
        for (int mi = 0; mi < 2; ++mi)
#pragma unroll
            for (int ni = 0; ni < 2; ++ni) {
                acc[mi][ni] = __builtin_amdgcn_mfma_f32_16x16x32_bf16(
                    a_h[mi], b_h[ni], acc[mi][ni], 0, 0, 0);
                acc[mi][ni] = __builtin_amdgcn_mfma_f32_16x16x32_bf16(
                    a_h[mi], b_l[ni], acc[mi][ni], 0, 0, 0);
                acc[mi][ni] = __builtin_amdgcn_mfma_f32_16x16x32_bf16(
                    a_l[mi], b_h[ni], acc[mi][ni], 0, 0, 0);
            }

        __syncthreads();
        cur ^= 1;
    }

    Ch += (long)z * sC; Cl += (long)z * sC;
#pragma unroll
    for (int mi = 0; mi < 2; ++mi) {
        const int row0 = bm + wm * 32 + mi * 16 + quad * 4;
#pragma unroll
        for (int ni = 0; ni < 2; ++ni) {
            const int col = bn + wn * 32 + ni * 16 + l16;
#pragma unroll
            for (int r = 0; r < 4; ++r) {
                const float v = acc[mi][ni][r];
                const long idx = (long)(row0 + r) * N + col;
                const __bf16 h = (__bf16)v;
                Ch[idx] = h;
                Cl[idx] = (__bf16)(v - (float)h);
            }
        }
    }
}

// ---------------- scores: S[z] = (XS_z @ Y_b^T)*alpha, fp32 out -------------
// 1-D grid 1024, XCD-aware decode: xcd=bid&7 owns z=2*xcd+(j>>6) (both z of
// one batch b=xcd share the Y panel) -> per-XCD L2 working set 3 MB.
__global__ __launch_bounds__(256) void mgemm_sc(
    const __bf16* __restrict__ Ah, const __bf16* __restrict__ Al,
    const __bf16* __restrict__ Bh, const __bf16* __restrict__ Bl,
    float* __restrict__ C, int N, int K,
    long sA1, long sA2, long sB1, long sC, float alpha) {
    constexpr int BM = 128, BK = 32, BN = 128;
    __shared__ __bf16 As[2 * BM * BK];
    __shared__ __bf16 Bs[2 * BN * BK];

    const int bid = blockIdx.x;
    const int xcd = bid & 7;
    const int j   = bid >> 3;
    const int z   = 2 * xcd + (j >> 6);
    const int t   = j & 63;
    const int bm  = (t >> 3) * BM;
    const int bn  = (t & 7) * BN;

    const long aoff = (long)(z >> 1) * sA1 + (long)(z & 1) * sA2;
    const long boff = (long)(z >> 1) * sB1;
    Ah += aoff; Al += aoff;
    Bh += boff; Bl += boff;

    const int tid = threadIdx.x;
    const int wave = tid >> 6, lane = tid & 63;
    const int wm = wave >> 1, wn = wave & 1;
    const int quad = lane >> 4, l16 = lane & 15;

    f32x4 acc[4][4];
#pragma unroll
    for (int i = 0; i < 4; ++i)
#pragma unroll
        for (int jj = 0; jj < 4; ++jj) acc[i][jj] = (f32x4){0.f, 0.f, 0.f, 0.f};

    const int srow = lane >> 2;
    const int slot = lane & 3;

    for (int k0 = 0; k0 < K; k0 += BK) {
        __syncthreads();
#pragma unroll
        for (int i = 0; i < 2; ++i) {
            const int r0 = wave * 32 + i * 16;
            const int row = r0 + srow;
            const int chunk = slot ^ ((row >> 1) & 3);
            const long ga = (long)(bm + row) * K + k0 + chunk * 8;
            gl_lds(Ah + ga, &As[r0 * 32]);
            gl_lds(Al + ga, &As[BM * BK + r0 * 32]);
            const long gb = (long)(bn + row) * K + k0 + chunk * 8;
            gl_lds(Bh + gb, &Bs[r0 * 32]);
            gl_lds(Bl + gb, &Bs[BN * BK + r0 * 32]);
        }
        __syncthreads();

        bf16x8 a_h[4], a_l[4], b_h[4], b_l[4];
#pragma unroll
        for (int mi = 0; mi < 4; ++mi) {
            const int row = wm * 64 + mi * 16 + l16;
            const int off = row * 32 + ((quad ^ ((row >> 1) & 3)) * 8);
            a_h[mi] = *(const bf16x8*)&As[off];
            a_l[mi] = *(const bf16x8*)&As[BM * BK + off];
        }
#pragma unroll
        for (int ni = 0; ni < 4; ++ni) {
            const int row = wn * 64 + ni * 16 + l16;
            const int off = row * 32 + ((quad ^ ((row >> 1) & 3)) * 8);
            b_h[ni] = *(const bf16x8*)&Bs[off];
            b_l[ni] = *(const bf16x8*)&Bs[BN * BK + off];
        }
#pragma unroll
        for (int mi = 0; mi < 4; ++mi)
#pragma unroll
            for (int ni = 0; ni < 4; ++ni) {
                acc[mi][ni] = __builtin_amdgcn_mfma_f32_16x16x32_bf16(
                    a_h[mi], b_h[ni], acc[mi][ni], 0, 0, 0);
                acc[mi][ni] = __builtin_amdgcn_mfma_f32_16x16x32_bf16(
                    a_h[mi], b_l[ni], acc[mi][ni], 0, 0, 0);
                acc[mi][ni] = __builtin_amdgcn_mfma_f32_16x16x32_bf16(
                    a_l[mi], b_h[ni], acc[mi][ni], 0, 0, 0);
            }
    }

    C += (long)z * sC;
#pragma unroll
    for (int mi = 0; mi < 4; ++mi) {
        const int row0 = bm + wm * 64 + mi * 16 + quad * 4;
#pragma unroll
        for (int ni = 0; ni < 4; ++ni) {
            const int col = bn + wn * 64 + ni * 16 + l16;
#pragma unroll
            for (int r = 0; r < 4; ++r)
                C[(long)(row0 + r) * NN_ + col] = acc[mi][ni][r] * alpha;
        }
    }
}

// ---------------- blendsm: softmax+blend+entropy+route, P -> global --------
// Grid 2048 x 256 thr (4 waves). Block owns (b = blk&7, rows 4*(blk>>3)..+3).
// Wave w owns one row fully: softmax/entropy/route wave-local, no barriers.
__global__ __launch_bounds__(256, 8) void blendsm_kernel(
    const float* __restrict__ S, const float* __restrict__ pos,
    const float* __restrict__ gating, const float* __restrict__ h_temp,
    __bf16* __restrict__ P, float* __restrict__ heat) {
    const int b = blockIdx.x & 7;
    const int n = (blockIdx.x >> 3) * 4 + (threadIdx.x >> 6);
    const int lane = threadIdx.x & 63;

    const float g = 1.f / (1.f + __expf(-gating[0]));
    const float cg = 1.f - g;
    const float ht = h_temp[0];

    const float* r0p = S + ((long)(b * 2 + 0) * NN_ + n) * NN_;
    const float* r1p = S + ((long)(b * 2 + 1) * NN_ + n) * NN_;

    f32x4 a0[4], a1[4];
#pragma unroll
    for (int j = 0; j < 4; ++j) {
        a0[j] = *(const f32x4*)(r0p + j * 256 + lane * 4);
        a1[j] = *(const f32x4*)(r1p + j * 256 + lane * 4);
    }
    // row max (in-wave)
    float m0 = -3.4e38f, m1 = -3.4e38f;
#pragma unroll
    for (int j = 0; j < 4; ++j) {
        m0 = fmaxf(m0, fmaxf(fmaxf(a0[j][0], a0[j][1]), fmaxf(a0[j][2], a0[j][3])));
        m1 = fmaxf(m1, fmaxf(fmaxf(a1[j][0], a1[j][1]), fmaxf(a1[j][2], a1[j][3])));
    }
    m0 = wred_max(m0); m1 = wred_max(m1);
    // exp + sum
    float s0 = 0.f, s1 = 0.f;
#pragma unroll
    for (int j = 0; j < 4; ++j) {
        a0[j][0] = __expf(a0[j][0] - m0); a0[j][1] = __expf(a0[j][1] - m0);
        a0[j][2] = __expf(a0[j][2] - m0); a0[j][3] = __expf(a0[j][3] - m0);
        s0 += a0[j][0] + a0[j][1] + a0[j][2] + a0[j][3];
        a1[j][0] = __expf(a1[j][0] - m1); a1[j][1] = __expf(a1[j][1] - m1);
        a1[j][2] = __expf(a1[j][2] - m1); a1[j][3] = __expf(a1[j][3] - m1);
        s1 += a1[j][0] + a1[j][1] + a1[j][2] + a1[j][3];
    }
    s0 = wred_sum(s0); s1 = wred_sum(s1);
    const float i0 = 1.f / s0, i1 = 1.f / s1;
    // blend + entropy
    const float* pr = pos + (long)n * NN_;
    float e0 = 0.f, e1 = 0.f;
#pragma unroll
    for (int j = 0; j < 4; ++j) {
        const f32x4 pv = *(const f32x4*)(pr + j * 256 + lane * 4);
        a0[j][0] = cg * a0[j][0] * i0 + g * pv[0];
        a0[j][1] = cg * a0[j][1] * i0 + g * pv[1];
        a0[j][2] = cg * a0[j][2] * i0 + g * pv[2];
        a0[j][3] = cg * a0[j][3] * i0 + g * pv[3];
        a1[j][0] = cg * a1[j][0] * i1 + g * pv[0];
        a1[j][1] = cg * a1[j][1] * i1 + g * pv[1];
        a1[j][2] = cg * a1[j][2] * i1 + g * pv[2];
        a1[j][3] = cg * a1[j][3] * i1 + g * pv[3];
        e0 -= a0[j][0] * __logf(a0[j][0] + 1e-8f) + a0[j][1] * __logf(a0[j][1] + 1e-8f) +
              a0[j][2] * __logf(a0[j][2] + 1e-8f) + a0[j][3] * __logf(a0[j][3] + 1e-8f);
        e1 -= a1[j][0] * __logf(a1[j][0] + 1e-8f) + a1[j][1] * __logf(a1[j][1] + 1e-8f) +
              a1[j][2] * __logf(a1[j][2] + 1e-8f) + a1[j][3] * __logf(a1[j][3] + 1e-8f);
    }
    e0 = wred_sum(e0); e1 = wred_sum(e1);
    const float hm0 = 2.f - 2.f / (1.f + __expf(-ht * e0));
    const float hm1 = 2.f - 2.f / (1.f + __expf(-ht * e1));
    const bool fg = (hm0 >= hm1);
    if (lane == 0) heat[(long)b * NN_ + n] = fg ? hm0 : hm1;
    // selected P row -> global bf16
    __bf16* prow = P + ((long)b * NN_ + n) * NN_;
#pragma unroll
    for (int j = 0; j < 4; ++j) {
        const f32x4 v = fg ? a0[j] : a1[j];
        bf16x4 o;
        o[0] = (__bf16)v[0]; o[1] = (__bf16)v[1];
        o[2] = (__bf16)v[2]; o[3] = (__bf16)v[3];
        *(bf16x4*)(prow + j * 256 + lane * 4) = o;
    }
}

// ---------------- pv_gemm v2: out[b] = P[b] @ yt[b]^T ---------------------
// BM32/BK32/BN64, 256 thr / 4 waves, double-buffered LDS (12 KB).
// 1-D grid 1024 = 8 b (bid&7, XCD-local) x 32 m x 4 n -> 4096 waves.
__global__ __launch_bounds__(256) void pv_gemm(
    const __bf16* __restrict__ A, const __bf16* __restrict__ Bm,
    float* __restrict__ C) {
    constexpr int BM = 32, BK = 32, BN = 64;
    __shared__ __bf16 As[2][BM * BK];
    __shared__ __bf16 Bs[2][BN * BK];

    const int bid = blockIdx.x;
    const int b   = bid & 7;
    const int j   = bid >> 3;           // 0..127
    const int bm  = (j >> 2) * BM;      // 32 m-tiles
    const int bn  = (j & 3) * BN;       // 4 n-tiles

    A  += (long)b * NN_ * NN_;
    Bm += (long)b * ND * NN_;
    C  += (long)b * NN_ * ND;

    const int tid = threadIdx.x;
    const int wave = tid >> 6, lane = tid & 63;
    const int wm = wave >> 1, wn = wave & 1;
    const int quad = lane >> 4, l16 = lane & 15;
    const int srow = lane >> 2, slot = lane & 3;

    f32x4 acc[2];
    acc[0] = (f32x4){0.f, 0.f, 0.f, 0.f};
    acc[1] = (f32x4){0.f, 0.f, 0.f, 0.f};

    auto stage = [&](int sel, int k0) {
        if (wave < 2) {                 // A: 32 rows = 2 waves x 16
            const int row = wave * 16 + srow;
            const int chunk = slot ^ ((row >> 1) & 3);
            gl_lds(A + (long)(bm + row) * NN_ + k0 + chunk * 8,
                   &As[sel][wave * 16 * 32]);
        }
        {                               // B: 64 rows = 4 waves x 16
            const int row = wave * 16 + srow;
            const int chunk = slot ^ ((row >> 1) & 3);
            gl_lds(Bm + (long)(bn + row) * NN_ + k0 + chunk * 8,
                   &Bs[sel][wave * 16 * 32]);
        }
    };

    stage(0, 0);
    __syncthreads();
    int cur = 0;
    for (int k0 = 0; k0 < NN_; k0 += BK) {
        if (k0 + BK < NN_) stage(cur ^ 1, k0 + BK);

        const int arow = wm * 16 + l16;
        const int aoff = arow * 32 + ((quad ^ ((arow >> 1) & 3)) * 8);
        bf16x8 a = *(const bf16x8*)&As[cur][aoff];
#pragma unroll
        for (int ni = 0; ni < 2; ++ni) {
            const int brow = wn * 32 + ni * 16 + l16;
            const int boff = brow * 32 + ((quad ^ ((brow >> 1) & 3)) * 8);
            bf16x8 bb = *(const bf16x8*)&Bs[cur][boff];
            acc[ni] = __builtin_amdgcn_mfma_f32_16x16x32_bf16(
                a, bb, acc[ni], 0, 0, 0);
        }

        __syncthreads();
        cur ^= 1;
    }

    const int row0 = bm + wm * 16 + quad * 4;
#pragma unroll
    for (int ni = 0; ni < 2; ++ni) {
        const int col = bn + wn * 32 + ni * 16 + l16;
#pragma unroll
        for (int r = 0; r < 4; ++r)
            C[(long)(row0 + r) * ND + col] = acc[ni][r];
    }
}

extern "C" void kernel_launch(void* const* d_in, const int* in_sizes, int n_in,
                              void* d_out, int out_size, void* d_ws, size_t ws_size,
                              hipStream_t stream) {
    const float* x      = (const float*)d_in[0];
    const float* y      = (const float*)d_in[1];
    const float* coords = (const float*)d_in[2];
    const float* U      = (const float*)d_in[3];
    const float* S1p    = (const float*)d_in[4];
    const float* S2p    = (const float*)d_in[5];
    const float* gating = (const float*)d_in[6];
    const float* h_temp = (const float*)d_in[7];
    const float* p_temp = (const float*)d_in[8];
    const float* pos_emb= (const float*)d_in[9];

    float* out  = (float*)d_out;
    float* heat = out + (long)NB * NN_ * ND;

    // workspace (~105 MB)
    char* ws = (char*)d_ws;
    const long MB = 1 << 20;
    float*  Sf  = (float*)(ws);               // 64 MB [16][1024][1024]
    float*  pos = (float*)(ws + 64 * MB);     // 4 MB
    __bf16* Xh  = (__bf16*)(ws + 68 * MB);    // 4 MB
    __bf16* Xl  = (__bf16*)(ws + 72 * MB);    // 4 MB
    __bf16* XSh = (__bf16*)(ws + 76 * MB);    // 8 MB [2][8192][256]
    __bf16* XSl = (__bf16*)(ws + 84 * MB);    // 8 MB
    __bf16* yt  = (__bf16*)(ws + 92 * MB);    // 4 MB [8][256][1024]
    __bf16* Yh  = (__bf16*)(ws + 96 * MB);    // 4 MB
    __bf16* Yl  = (__bf16*)(ws + 100 * MB);   // 4 MB
    __bf16* Mh  = (__bf16*)(ws + 104 * MB);   // 256 KB [2][256][256]
    __bf16* Ml  = Mh + 2 * 65536;             // 256 KB
    // P overlays XSh/XSl (16 MB, dead after mgemm_sc)
    __bf16* Pb  = (__bf16*)(ws + 76 * MB);    // 16 MB [8][1024][1024]

    const long ND2 = (long)NN_ * ND;          // 262144
    const long BND = (long)NB * ND2;          // 2097152

    // 1) fused prep
    prep_kernel<<<dim3(2304), 256, 0, stream>>>(
        coords, pos_emb, p_temp, x, y, U, S1p, S2p,
        pos, Xh, Xl, yt, Yh, Yl, Mh, Ml);

    // 2) xs_k = x @ M_k  -> XS [2][8192][256]
    mgemm_xs<<<dim3(4, 128, 2), 256, 0, stream>>>(
        Xh, Xl, Mh, Ml, XSh, XSl, NB * NN_, ND, ND, 65536, BND);

    // 3) scores: S[b*2+br] = (XS_br[b] @ Y[b]^T) * D^-0.5  (XCD-swizzled)
    mgemm_sc<<<dim3(1024), 256, 0, stream>>>(
        XSh, XSl, Yh, Yl, Sf, NN_, ND,
        ND2, BND, ND2, (long)NN_ * NN_, 0.0625f);

    // 4) blend + entropy + route -> P (bf16), heat
    blendsm_kernel<<<dim3(2048), 256, 0, stream>>>(
        Sf, pos, gating, h_temp, Pb, heat);

    // 5) out[b] = P[b] @ yt[b]^T  (XCD-local)
    pv_gemm<<<dim3(1024), 256, 0, stream>>>(Pb, yt, out);

    (void)in_sizes; (void)n_in; (void)out_size; (void)ws_size;
}

// Round 14
// 187.823 us; speedup vs baseline: 1.1172x; 1.0757x over previous
//
#include <hip/hip_runtime.h>
#include <hip/hip_bf16.h>
#include <stdint.h>

// B=8, N=1024, D=256, fp32 in/out.
// R24: prep fixed per R23 counters (prep ~43us, 25% occ, 1.1 TB/s,
// latency-bound): (1) M-build moved to bids 0..255 so its latency tail
// runs FIRST, hidden under the 2048 streaming blocks behind it;
// (2) M-build LDS-staged: 16 U-rows (16KB) bulk-copied per chunk, the
// 256-step fmaf chain reads LDS (broadcast + conflict-free) in the SAME
// c-order -> bit-identical M. All other kernels = best-measured config.
// dur_us includes the harness's fixed 41 us workspace-poison fill.
// 5 dispatches: prep -> xs mgemm -> scores mgemm -> blendsm -> pv_gemm.

#define NB 8
#define NN_ 1024
#define ND 256

typedef __bf16 bf16x8 __attribute__((ext_vector_type(8)));
typedef __bf16 bf16x4 __attribute__((ext_vector_type(4)));
typedef float f32x4 __attribute__((ext_vector_type(4)));

// ---------------- async global->LDS (16B per lane) ----------------
__device__ inline void gl_lds(const __bf16* g, __bf16* l) {
    auto gp = (const __attribute__((address_space(1))) uint32_t*)(uintptr_t)g;
    auto lp = (__attribute__((address_space(3))) uint32_t*)(uintptr_t)l;
    __builtin_amdgcn_global_load_lds(gp, lp, 16, 0, 0);
}

// ---------------- reductions ----------------
__device__ inline float wred_sum(float v) {
#pragma unroll
    for (int o = 32; o; o >>= 1) v += __shfl_xor(v, o, 64);
    return v;
}
__device__ inline float wred_max(float v) {
#pragma unroll
    for (int o = 32; o; o >>= 1) v = fmaxf(v, __shfl_xor(v, o, 64));
    return v;
}

// ---------------- fused prep: build M | pos softmax | x split | y prep -----
// Section order (by bid): M 0..255 (latency-heavy, dispatched first so the
// streaming sections hide it), pos 256..1279, x 1280..1791, y 1792..2303.
__global__ __launch_bounds__(256) void prep_kernel(
    const float* __restrict__ coords, const float* __restrict__ pos_emb,
    const float* __restrict__ p_temp, const float* __restrict__ x,
    const float* __restrict__ y, const float* __restrict__ U,
    const float* __restrict__ S1, const float* __restrict__ S2,
    float* __restrict__ posS, __bf16* __restrict__ Xh, __bf16* __restrict__ Xl,
    __bf16* __restrict__ yt, __bf16* __restrict__ Yh, __bf16* __restrict__ Yl,
    __bf16* __restrict__ Mh, __bf16* __restrict__ Ml) {
    __shared__ char sm[18432];   // M: Us[16][256]f + s1s[256]f + s2s[256]f
    const int bid = blockIdx.x;
    const int tid = threadIdx.x;

    if (bid < 256) {
        // ---- M-build, LDS-staged, same c-order as before (bit-identical) --
        float* Us  = (float*)sm;          // [16][256]
        float* s1s = Us + 16 * 256;       // [256]
        float* s2s = s1s + 256;           // [256]
        const int n = bid, j = tid;
        s1s[tid] = fabsf(S1[tid]);
        s2s[tid] = fabsf(S2[tid]);
        float a1 = 0.f, a2 = 0.f;
        for (int c0 = 0; c0 < ND; c0 += 16) {
            __syncthreads();              // protect prev chunk + s1s/s2s
#pragma unroll
            for (int k = 0; k < 4; ++k) {
                const int idx = k * 256 + tid;   // float4 index 0..1023
                ((float4*)Us)[idx] =
                    ((const float4*)(U + (long)c0 * ND))[idx];
            }
            __syncthreads();
#pragma unroll
            for (int cc = 0; cc < 16; ++cc) {
                const float un = Us[cc * 256 + n];
                const float uj = Us[cc * 256 + j];
                a1 = fmaf(s1s[c0 + cc] * un, uj, a1);
                a2 = fmaf(s2s[c0 + cc] * un, uj, a2);
            }
        }
        const __bf16 h1 = (__bf16)a1, h2 = (__bf16)a2;
        Mh[n * ND + j] = h1;           Ml[n * ND + j] = (__bf16)(a1 - (float)h1);
        Mh[65536 + n * ND + j] = h2;   Ml[65536 + n * ND + j] = (__bf16)(a2 - (float)h2);
    } else if (bid < 1280) {
        float* red = (float*)sm;
        const int n = bid - 256;
        const float pt = -fabsf(p_temp[0]);
        float pe[6];
#pragma unroll
        for (int c = 0; c < 6; ++c) pe[c] = pos_emb[n * 6 + c];
        const float* cr = coords + (long)n * NN_ * 6;
        float l[4];
#pragma unroll
        for (int j = 0; j < 4; ++j) {
            const int m = j * 256 + tid;
            const float2* cp = (const float2*)(cr + (long)m * 6);
            float2 c0 = cp[0], c1 = cp[1], c2 = cp[2];
            l[j] = pt * (c0.x * pe[0] + c0.y * pe[1] + c1.x * pe[2] +
                         c1.y * pe[3] + c2.x * pe[4] + c2.y * pe[5]);
        }
        float mx = fmaxf(fmaxf(l[0], l[1]), fmaxf(l[2], l[3]));
        mx = wred_max(mx);
        __syncthreads();
        if ((tid & 63) == 0) red[tid >> 6] = mx;
        __syncthreads();
        mx = fmaxf(fmaxf(red[0], red[1]), fmaxf(red[2], red[3]));
        float e[4], s = 0.f;
#pragma unroll
        for (int j = 0; j < 4; ++j) { e[j] = __expf(l[j] - mx); s += e[j]; }
        s = wred_sum(s);
        __syncthreads();
        if ((tid & 63) == 0) red[4 + (tid >> 6)] = s;
        __syncthreads();
        s = red[4] + red[5] + red[6] + red[7];
        const float inv = 1.f / s;
#pragma unroll
        for (int j = 0; j < 4; ++j)
            posS[(long)n * NN_ + j * 256 + tid] = e[j] * inv;
    } else if (bid < 1792) {
        const int n4 = NB * NN_ * ND / 4;
        int i = (bid - 1280) * 256 + tid;
        for (; i < n4; i += 512 * 256) {
            float4 v = ((const float4*)x)[i];
            bf16x4 h, l;
            h[0] = (__bf16)v.x; l[0] = (__bf16)(v.x - (float)h[0]);
            h[1] = (__bf16)v.y; l[1] = (__bf16)(v.y - (float)h[1]);
            h[2] = (__bf16)v.z; l[2] = (__bf16)(v.z - (float)h[2]);
            h[3] = (__bf16)v.w; l[3] = (__bf16)(v.w - (float)h[3]);
            ((bf16x4*)Xh)[i] = h;
            ((bf16x4*)Xl)[i] = l;
        }
    } else {
        __bf16 (*t)[72] = (__bf16(*)[72])sm;
        const int rem = bid - 1792;
        const int b = rem >> 6;
        const int m0 = (rem & 15) * 64, d0 = ((rem >> 4) & 3) * 64;
        const int c = tid & 15;
        const int r = tid >> 4;
#pragma unroll
        for (int p = 0; p < 4; ++p) {
            const int row = r + p * 16;
            const long gi = ((long)b * NN_ + m0 + row) * ND + d0 + c * 4;
            float4 v = *(const float4*)(y + gi);
            bf16x4 h, l;
            h[0] = (__bf16)v.x; l[0] = (__bf16)(v.x - (float)h[0]);
            h[1] = (__bf16)v.y; l[1] = (__bf16)(v.y - (float)h[1]);
            h[2] = (__bf16)v.z; l[2] = (__bf16)(v.z - (float)h[2]);
            h[3] = (__bf16)v.w; l[3] = (__bf16)(v.w - (float)h[3]);
            *(bf16x4*)(Yh + gi) = h;
            *(bf16x4*)(Yl + gi) = l;
            t[c * 4 + 0][row] = h[0]; t[c * 4 + 1][row] = h[1];
            t[c * 4 + 2][row] = h[2]; t[c * 4 + 3][row] = h[3];
        }
        __syncthreads();
#pragma unroll
        for (int p = 0; p < 4; ++p) {
            const int d = r + p * 16;
            bf16x4 o;
            o[0] = t[d][c * 4 + 0]; o[1] = t[d][c * 4 + 1];
            o[2] = t[d][c * 4 + 2]; o[3] = t[d][c * 4 + 3];
            *(bf16x4*)(yt + ((long)b * ND + d0 + d) * NN_ + m0 + c * 4) = o;
        }
    }
}

// ---------------- xs = x @ M_k (split x3, bf16 h/l out) ----------------
// BM64/BN64/BK32, grid (4,128,2)=1024 blocks -> 4096 waves (16/CU).
// Double-buffered LDS (32 KB), stage-before-compute, 1 barrier/K-step.
__global__ __launch_bounds__(256) void mgemm_xs(
    const __bf16* __restrict__ Ah, const __bf16* __restrict__ Al,
    const __bf16* __restrict__ Bh, const __bf16* __restrict__ Bl,
    __bf16* __restrict__ Ch, __bf16* __restrict__ Cl,
    int M, int N, int K, long sB1, long sC) {
    constexpr int BM = 64, BK = 32, BN = 64;
    __shared__ __bf16 As[2][2 * BM * BK];   // [buf][h:0 | l:BM*BK]
    __shared__ __bf16 Bs[2][2 * BN * BK];

    const int z = blockIdx.z;
    Bh += (long)z * sB1; Bl += (long)z * sB1;

    const int tid = threadIdx.x;
    const int bm = blockIdx.y * BM, bn = blockIdx.x * BN;
    const int wave = tid >> 6, lane = tid & 63;
    const int wm = wave >> 1, wn = wave & 1;
    const int quad = lane >> 4, l16 = lane & 15;
    const int srow = lane >> 2, slot = lane & 3;

    f32x4 acc[2][2];
#pragma unroll
    for (int i = 0; i < 2; ++i)
#pragma unroll
        for (int j = 0; j < 2; ++j) acc[i][j] = (f32x4){0.f, 0.f, 0.f, 0.f};

    auto stage = [&](int sel, int k0) {
        const int r0 = wave * 16;
        const int row = r0 + srow;
        const int chunk = slot ^ ((row >> 1) & 3);
        const long ga = (long)(bm + row) * K + k0 + chunk * 8;
        gl_lds(Ah + ga, &As[sel][r0 * 32]);
        gl_lds(Al + ga, &As[sel][BM * BK + r0 * 32]);
        const long gb = (long)(bn + row) * K + k0 + chunk * 8;
        gl_lds(Bh + gb, &Bs[sel][r0 * 32]);
        gl_lds(Bl + gb, &Bs[sel][BN * BK + r0 * 32]);
    };

    stage(0, 0);
    __syncthreads();
    int cur = 0;
    for (int k0 = 0; k0 < K; k0 += BK) {
        if (k0 + BK < K) stage(cur ^ 1, k0 + BK);

        bf16x8 a_h[2], a_l[2], b_h[2], b_l[2];
#pragma unroll
        for (int mi = 0; mi < 2; ++mi) {
            const int row = wm * 32 + mi * 16 + l16;
            const int off = row * 32 + ((quad ^ ((row >> 1) & 3)) * 8);
            a_h[mi] = *(const bf16x8*)&As[cur][off];
            a_l[mi] = *(const bf16x8*)&As[cur][BM * BK + off];
        }
#pragma unroll
        for (int ni = 0; ni < 2; ++ni) {
            const int row = wn * 32 + ni * 16 + l16;
            const int off = row * 32 + ((quad ^ ((row >> 1) & 3)) * 8);
            b_h[ni] = *(const bf16x8*)&Bs[cur][off];
            b_l[ni] = *(const bf16x8*)&Bs[cur][BN * BK + off];
        }
#pragma unroll
        for (int mi = 0; mi < 2; ++mi)
#pragma unroll
            for (int ni = 0; ni < 2; ++ni) {
                acc[mi][ni] = __builtin_amdgcn_mfma_f32_16x16x32_bf16(
                    a_h[mi], b_h[ni], acc[mi][ni], 0, 0, 0);
                acc[mi][ni] = __builtin_amdgcn_mfma_f32_16x16x32_bf16(
                    a_h[mi], b_l[ni], acc[mi][ni], 0, 0, 0);
                acc[mi][ni] = __builtin_amdgcn_mfma_f32_16x16x32_bf16(
                    a_l[mi], b_h[ni], acc[mi][ni], 0, 0, 0);
            }

        __syncthreads();
        cur ^= 1;
    }

    Ch += (long)z * sC; Cl += (long)z * sC;
#pragma unroll
    for (int mi = 0; mi < 2; ++mi) {
        const int row0 = bm + wm * 32 + mi * 16 + quad * 4;
#pragma unroll
        for (int ni = 0; ni < 2; ++ni) {
            const int col = bn + wn * 32 + ni * 16 + l16;
#pragma unroll
            for (int r = 0; r < 4; ++r) {
                const float v = acc[mi][ni][r];
                const long idx = (long)(row0 + r) * N + col;
                const __bf16 h = (__bf16)v;
                Ch[idx] = h;
                Cl[idx] = (__bf16)(v - (float)h);
            }
        }
    }
}

// ---------------- scores: S[z] = (XS_z @ Y_b^T)*alpha, fp32 out -------------
// 1-D grid 1024, XCD-aware decode: xcd=bid&7 owns z=2*xcd+(j>>6) (both z of
// one batch b=xcd share the Y panel) -> per-XCD L2 working set 3 MB.
__global__ __launch_bounds__(256) void mgemm_sc(
    const __bf16* __restrict__ Ah, const __bf16* __restrict__ Al,
    const __bf16* __restrict__ Bh, const __bf16* __restrict__ Bl,
    float* __restrict__ C, int N, int K,
    long sA1, long sA2, long sB1, long sC, float alpha) {
    constexpr int BM = 128, BK = 32, BN = 128;
    __shared__ __bf16 As[2 * BM * BK];
    __shared__ __bf16 Bs[2 * BN * BK];

    const int bid = blockIdx.x;
    const int xcd = bid & 7;
    const int j   = bid >> 3;
    const int z   = 2 * xcd + (j >> 6);
    const int t   = j & 63;
    const int bm  = (t >> 3) * BM;
    const int bn  = (t & 7) * BN;

    const long aoff = (long)(z >> 1) * sA1 + (long)(z & 1) * sA2;
    const long boff = (long)(z >> 1) * sB1;
    Ah += aoff; Al += aoff;
    Bh += boff; Bl += boff;

    const int tid = threadIdx.x;
    const int wave = tid >> 6, lane = tid & 63;
    const int wm = wave >> 1, wn = wave & 1;
    const int quad = lane >> 4, l16 = lane & 15;

    f32x4 acc[4][4];
#pragma unroll
    for (int i = 0; i < 4; ++i)
#pragma unroll
        for (int jj = 0; jj < 4; ++jj) acc[i][jj] = (f32x4){0.f, 0.f, 0.f, 0.f};

    const int srow = lane >> 2;
    const int slot = lane & 3;

    for (int k0 = 0; k0 < K; k0 += BK) {
        __syncthreads();
#pragma unroll
        for (int i = 0; i < 2; ++i) {
            const int r0 = wave * 32 + i * 16;
            const int row = r0 + srow;
            const int chunk = slot ^ ((row >> 1) & 3);
            const long ga = (long)(bm + row) * K + k0 + chunk * 8;
            gl_lds(Ah + ga, &As[r0 * 32]);
            gl_lds(Al + ga, &As[BM * BK + r0 * 32]);
            const long gb = (long)(bn + row) * K + k0 + chunk * 8;
            gl_lds(Bh + gb, &Bs[r0 * 32]);
            gl_lds(Bl + gb, &Bs[BN * BK + r0 * 32]);
        }
        __syncthreads();

        bf16x8 a_h[4], a_l[4], b_h[4], b_l[4];
#pragma unroll
        for (int mi = 0; mi < 4; ++mi) {
            const int row = wm * 64 + mi * 16 + l16;
            const int off = row * 32 + ((quad ^ ((row >> 1) & 3)) * 8);
            a_h[mi] = *(const bf16x8*)&As[off];
            a_l[mi] = *(const bf16x8*)&As[BM * BK + off];
        }
#pragma unroll
        for (int ni = 0; ni < 4; ++ni) {
            const int row = wn * 64 + ni * 16 + l16;
            const int off = row * 32 + ((quad ^ ((row >> 1) & 3)) * 8);
            b_h[ni] = *(const bf16x8*)&Bs[off];
            b_l[ni] = *(const bf16x8*)&Bs[BN * BK + off];
        }
#pragma unroll
        for (int mi = 0; mi < 4; ++mi)
#pragma unroll
            for (int ni = 0; ni < 4; ++ni) {
                acc[mi][ni] = __builtin_amdgcn_mfma_f32_16x16x32_bf16(
                    a_h[mi], b_h[ni], acc[mi][ni], 0, 0, 0);
                acc[mi][ni] = __builtin_amdgcn_mfma_f32_16x16x32_bf16(
                    a_h[mi], b_l[ni], acc[mi][ni], 0, 0, 0);
                acc[mi][ni] = __builtin_amdgcn_mfma_f32_16x16x32_bf16(
                    a_l[mi], b_h[ni], acc[mi][ni], 0, 0, 0);
            }
    }

    C += (long)z * sC;
#pragma unroll
    for (int mi = 0; mi < 4; ++mi) {
        const int row0 = bm + wm * 64 + mi * 16 + quad * 4;
#pragma unroll
        for (int ni = 0; ni < 4; ++ni) {
            const int col = bn + wn * 64 + ni * 16 + l16;
#pragma unroll
            for (int r = 0; r < 4; ++r)
                C[(long)(row0 + r) * NN_ + col] = acc[mi][ni][r] * alpha;
        }
    }
}

// ---------------- blendsm: softmax+blend+entropy+route, P -> global --------
// Grid 2048 x 256 thr (4 waves). Block owns (b = blk&7, rows 4*(blk>>3)..+3).
// Wave w owns one row fully: softmax/entropy/route wave-local, no barriers.
__global__ __launch_bounds__(256, 8) void blendsm_kernel(
    const float* __restrict__ S, const float* __restrict__ pos,
    const float* __restrict__ gating, const float* __restrict__ h_temp,
    __bf16* __restrict__ P, float* __restrict__ heat) {
    const int b = blockIdx.x & 7;
    const int n = (blockIdx.x >> 3) * 4 + (threadIdx.x >> 6);
    const int lane = threadIdx.x & 63;

    const float g = 1.f / (1.f + __expf(-gating[0]));
    const float cg = 1.f - g;
    const float ht = h_temp[0];

    const float* r0p = S + ((long)(b * 2 + 0) * NN_ + n) * NN_;
    const float* r1p = S + ((long)(b * 2 + 1) * NN_ + n) * NN_;

    f32x4 a0[4], a1[4];
#pragma unroll
    for (int j = 0; j < 4; ++j) {
        a0[j] = *(const f32x4*)(r0p + j * 256 + lane * 4);
        a1[j] = *(const f32x4*)(r1p + j * 256 + lane * 4);
    }
    // row max (in-wave)
    float m0 = -3.4e38f, m1 = -3.4e38f;
#pragma unroll
    for (int j = 0; j < 4; ++j) {
        m0 = fmaxf(m0, fmaxf(fmaxf(a0[j][0], a0[j][1]), fmaxf(a0[j][2], a0[j][3])));
        m1 = fmaxf(m1, fmaxf(fmaxf(a1[j][0], a1[j][1]), fmaxf(a1[j][2], a1[j][3])));
    }
    m0 = wred_max(m0); m1 = wred_max(m1);
    // exp + sum
    float s0 = 0.f, s1 = 0.f;
#pragma unroll
    for (int j = 0; j < 4; ++j) {
        a0[j][0] = __expf(a0[j][0] - m0); a0[j][1] = __expf(a0[j][1] - m0);
        a0[j][2] = __expf(a0[j][2] - m0); a0[j][3] = __expf(a0[j][3] - m0);
        s0 += a0[j][0] + a0[j][1] + a0[j][2] + a0[j][3];
        a1[j][0] = __expf(a1[j][0] - m1); a1[j][1] = __expf(a1[j][1] - m1);
        a1[j][2] = __expf(a1[j][2] - m1); a1[j][3] = __expf(a1[j][3] - m1);
        s1 += a1[j][0] + a1[j][1] + a1[j][2] + a1[j][3];
    }
    s0 = wred_sum(s0); s1 = wred_sum(s1);
    const float i0 = 1.f / s0, i1 = 1.f / s1;
    // blend + entropy
    const float* pr = pos + (long)n * NN_;
    float e0 = 0.f, e1 = 0.f;
#pragma unroll
    for (int j = 0; j < 4; ++j) {
        const f32x4 pv = *(const f32x4*)(pr + j * 256 + lane * 4);
        a0[j][0] = cg * a0[j][0] * i0 + g * pv[0];
        a0[j][1] = cg * a0[j][1] * i0 + g * pv[1];
        a0[j][2] = cg * a0[j][2] * i0 + g * pv[2];
        a0[j][3] = cg * a0[j][3] * i0 + g * pv[3];
        a1[j][0] = cg * a1[j][0] * i1 + g * pv[0];
        a1[j][1] = cg * a1[j][1] * i1 + g * pv[1];
        a1[j][2] = cg * a1[j][2] * i1 + g * pv[2];
        a1[j][3] = cg * a1[j][3] * i1 + g * pv[3];
        e0 -= a0[j][0] * __logf(a0[j][0] + 1e-8f) + a0[j][1] * __logf(a0[j][1] + 1e-8f) +
              a0[j][2] * __logf(a0[j][2] + 1e-8f) + a0[j][3] * __logf(a0[j][3] + 1e-8f);
        e1 -= a1[j][0] * __logf(a1[j][0] + 1e-8f) + a1[j][1] * __logf(a1[j][1] + 1e-8f) +
              a1[j][2] * __logf(a1[j][2] + 1e-8f) + a1[j][3] * __logf(a1[j][3] + 1e-8f);
    }
    e0 = wred_sum(e0); e1 = wred_sum(e1);
    const float hm0 = 2.f - 2.f / (1.f + __expf(-ht * e0));
    const float hm1 = 2.f - 2.f / (1.f + __expf(-ht * e1));
    const bool fg = (hm0 >= hm1);
    if (lane == 0) heat[(long)b * NN_ + n] = fg ? hm0 : hm1;
    // selected P row -> global bf16
    __bf16* prow = P + ((long)b * NN_ + n) * NN_;
#pragma unroll
    for (int j = 0; j < 4; ++j) {
        const f32x4 v = fg ? a0[j] : a1[j];
        bf16x4 o;
        o[0] = (__bf16)v[0]; o[1] = (__bf16)v[1];
        o[2] = (__bf16)v[2]; o[3] = (__bf16)v[3];
        *(bf16x4*)(prow + j * 256 + lane * 4) = o;
    }
}

// ---------------- pv_gemm v2: out[b] = P[b] @ yt[b]^T ---------------------
// BM32/BK32/BN64, 256 thr / 4 waves, double-buffered LDS (12 KB).
// 1-D grid 1024 = 8 b (bid&7, XCD-local) x 32 m x 4 n -> 4096 waves.
__global__ __launch_bounds__(256) void pv_gemm(
    const __bf16* __restrict__ A, const __bf16* __restrict__ Bm,
    float* __restrict__ C) {
    constexpr int BM = 32, BK = 32, BN = 64;
    __shared__ __bf16 As[2][BM * BK];
    __shared__ __bf16 Bs[2][BN * BK];

    const int bid = blockIdx.x;
    const int b   = bid & 7;
    const int j   = bid >> 3;           // 0..127
    const int bm  = (j >> 2) * BM;      // 32 m-tiles
    const int bn  = (j & 3) * BN;       // 4 n-tiles

    A  += (long)b * NN_ * NN_;
    Bm += (long)b * ND * NN_;
    C  += (long)b * NN_ * ND;

    const int tid = threadIdx.x;
    const int wave = tid >> 6, lane = tid & 63;
    const int wm = wave >> 1, wn = wave & 1;
    const int quad = lane >> 4, l16 = lane & 15;
    const int srow = lane >> 2, slot = lane & 3;

    f32x4 acc[2];
    acc[0] = (f32x4){0.f, 0.f, 0.f, 0.f};
    acc[1] = (f32x4){0.f, 0.f, 0.f, 0.f};

    auto stage = [&](int sel, int k0) {
        if (wave < 2) {                 // A: 32 rows = 2 waves x 16
            const int row = wave * 16 + srow;
            const int chunk = slot ^ ((row >> 1) & 3);
            gl_lds(A + (long)(bm + row) * NN_ + k0 + chunk * 8,
                   &As[sel][wave * 16 * 32]);
        }
        {                               // B: 64 rows = 4 waves x 16
            const int row = wave * 16 + srow;
            const int chunk = slot ^ ((row >> 1) & 3);
            gl_lds(Bm + (long)(bn + row) * NN_ + k0 + chunk * 8,
                   &Bs[sel][wave * 16 * 32]);
        }
    };

    stage(0, 0);
    __syncthreads();
    int cur = 0;
    for (int k0 = 0; k0 < NN_; k0 += BK) {
        if (k0 + BK < NN_) stage(cur ^ 1, k0 + BK);

        const int arow = wm * 16 + l16;
        const int aoff = arow * 32 + ((quad ^ ((arow >> 1) & 3)) * 8);
        bf16x8 a = *(const bf16x8*)&As[cur][aoff];
#pragma unroll
        for (int ni = 0; ni < 2; ++ni) {
            const int brow = wn * 32 + ni * 16 + l16;
            const int boff = brow * 32 + ((quad ^ ((brow >> 1) & 3)) * 8);
            bf16x8 bb = *(const bf16x8*)&Bs[cur][boff];
            acc[ni] = __builtin_amdgcn_mfma_f32_16x16x32_bf16(
                a, bb, acc[ni], 0, 0, 0);
        }

        __syncthreads();
        cur ^= 1;
    }

    const int row0 = bm + wm * 16 + quad * 4;
#pragma unroll
    for (int ni = 0; ni < 2; ++ni) {
        const int col = bn + wn * 32 + ni * 16 + l16;
#pragma unroll
        for (int r = 0; r < 4; ++r)
            C[(long)(row0 + r) * ND + col] = acc[ni][r];
    }
}

extern "C" void kernel_launch(void* const* d_in, const int* in_sizes, int n_in,
                              void* d_out, int out_size, void* d_ws, size_t ws_size,
                              hipStream_t stream) {
    const float* x      = (const float*)d_in[0];
    const float* y      = (const float*)d_in[1];
    const float* coords = (const float*)d_in[2];
    const float* U      = (const float*)d_in[3];
    const float* S1p    = (const float*)d_in[4];
    const float* S2p    = (const float*)d_in[5];
    const float* gating = (const float*)d_in[6];
    const float* h_temp = (const float*)d_in[7];
    const float* p_temp = (const float*)d_in[8];
    const float* pos_emb= (const float*)d_in[9];

    float* out  = (float*)d_out;
    float* heat = out + (long)NB * NN_ * ND;

    // workspace (~105 MB)
    char* ws = (char*)d_ws;
    const long MB = 1 << 20;
    float*  Sf  = (float*)(ws);               // 64 MB [16][1024][1024]
    float*  pos = (float*)(ws + 64 * MB);     // 4 MB
    __bf16* Xh  = (__bf16*)(ws + 68 * MB);    // 4 MB
    __bf16* Xl  = (__bf16*)(ws + 72 * MB);    // 4 MB
    __bf16* XSh = (__bf16*)(ws + 76 * MB);    // 8 MB [2][8192][256]
    __bf16* XSl = (__bf16*)(ws + 84 * MB);    // 8 MB
    __bf16* yt  = (__bf16*)(ws + 92 * MB);    // 4 MB [8][256][1024]
    __bf16* Yh  = (__bf16*)(ws + 96 * MB);    // 4 MB
    __bf16* Yl  = (__bf16*)(ws + 100 * MB);   // 4 MB
    __bf16* Mh  = (__bf16*)(ws + 104 * MB);   // 256 KB [2][256][256]
    __bf16* Ml  = Mh + 2 * 65536;             // 256 KB
    // P overlays XSh/XSl (16 MB, dead after mgemm_sc)
    __bf16* Pb  = (__bf16*)(ws + 76 * MB);    // 16 MB [8][1024][1024]

    const long ND2 = (long)NN_ * ND;          // 262144
    const long BND = (long)NB * ND2;          // 2097152

    // 1) fused prep (M first, then pos/x/y streaming)
    prep_kernel<<<dim3(2304), 256, 0, stream>>>(
        coords, pos_emb, p_temp, x, y, U, S1p, S2p,
        pos, Xh, Xl, yt, Yh, Yl, Mh, Ml);

    // 2) xs_k = x @ M_k  -> XS [2][8192][256]
    mgemm_xs<<<dim3(4, 128, 2), 256, 0, stream>>>(
        Xh, Xl, Mh, Ml, XSh, XSl, NB * NN_, ND, ND, 65536, BND);

    // 3) scores: S[b*2+br] = (XS_br[b] @ Y[b]^T) * D^-0.5  (XCD-swizzled)
    mgemm_sc<<<dim3(1024), 256, 0, stream>>>(
        XSh, XSl, Yh, Yl, Sf, NN_, ND,
        ND2, BND, ND2, (long)NN_ * NN_, 0.0625f);

    // 4) blend + entropy + route -> P (bf16), heat
    blendsm_kernel<<<dim3(2048), 256, 0, stream>>>(
        Sf, pos, gating, h_temp, Pb, heat);

    // 5) out[b] = P[b] @ yt[b]^T  (XCD-local)
    pv_gemm<<<dim3(1024), 256, 0, stream>>>(Pb, yt, out);

    (void)in_sizes; (void)n_in; (void)out_size; (void)ws_size;
}